// Round 5
// baseline (139.585 us; speedup 1.0000x reference)
//
#include <hip/hip_runtime.h>

// Problem constants
#define BB   4
#define NN   30000
#define TT   12
#define EE   240000
#define FT   24        // F_IN * T floats per (b, node)
#define NM   96        // BB * FT
#define CAP  32        // bucket capacity per node (deg ~ Poisson(8); max ~22)
#define OVCAP 2048     // overflow capacity (normally 0 used)
#define FB   ((EE + 1023) / 1024)    // 235 fill blocks (4 edges/thread)
#define LOG2E 1.44269504088896340736f
#define NPW  4                       // nodes per wave (software pipeline depth)

// Workspace layout (4-byte elements), total ~4 MB:
//   cnt[NN]          @ 0            (zeroed by memset)
//   ovf_cnt[16]      @ 30000        (zeroed by memset; [0] used)
//   eff[256]  float  @ 30016
//   ovf[2*OVCAP] int @ 30272        ((dst,src) pairs)
//   bucket[NN*CAP]   @ 34368
#define WS_CNT 0
#define WS_OVC 30000
#define WS_EFF 30016
#define WS_OVF 30272
#define WS_BKT 34368

__device__ __forceinline__ float readlane_f(float v, int l) {
    return __int_as_float(__builtin_amdgcn_readlane(__float_as_int(v), l));
}
__device__ __forceinline__ float rfl_f(float v) {
    return __int_as_float(__builtin_amdgcn_readfirstlane(__float_as_int(v)));
}

// ---- one launch: bucket-fill (4 edges/thread) | weight fold ---------------
// eff layout: Az0[32] Az1[32] ab[32] Ch0[32] Ch1[32] cb[32] probs[12]
// where A* = -log2e * (Wz folded), C* = 2*log2e * (Wh folded):
//   a = Az0*v0 + Az1*v1 + ab  -> u  = exp2(a) = exp(-zp)
//   c = Ch0*v0 + Ch1*v1 + cb  -> e2 = exp2(c) = exp(2*hp)
__global__ void __launch_bounds__(256)
k_pre(const int* __restrict__ src, const int* __restrict__ dst,
      const float* __restrict__ czw, const float* __restrict__ czb,
      const float* __restrict__ lzw, const float* __restrict__ lzb,
      const float* __restrict__ chw, const float* __restrict__ chb,
      const float* __restrict__ lhw, const float* __restrict__ lhb,
      const float* __restrict__ att,
      int* __restrict__ cnt, int* __restrict__ ovc,
      int* __restrict__ ovf, int* __restrict__ bucket, float* __restrict__ eff) {
    int bid = blockIdx.x, lt = threadIdx.x;
    if (bid < FB) {
        int e = bid * 1024 + lt * 4;           // EE % 4 == 0 -> all-or-nothing
        if (e < EE) {
            int4 s4 = *(const int4*)(src + e);
            int4 d4 = *(const int4*)(dst + e);
            // 4 independent atomic chains in flight
            int sl0 = atomicAdd(&cnt[d4.x], 1);
            int sl1 = atomicAdd(&cnt[d4.y], 1);
            int sl2 = atomicAdd(&cnt[d4.z], 1);
            int sl3 = atomicAdd(&cnt[d4.w], 1);
            if (sl0 < CAP) bucket[d4.x * CAP + sl0] = s4.x;
            else { int o = atomicAdd(ovc, 1); if (o < OVCAP) { ovf[2*o] = d4.x; ovf[2*o+1] = s4.x; } }
            if (sl1 < CAP) bucket[d4.y * CAP + sl1] = s4.y;
            else { int o = atomicAdd(ovc, 1); if (o < OVCAP) { ovf[2*o] = d4.y; ovf[2*o+1] = s4.y; } }
            if (sl2 < CAP) bucket[d4.z * CAP + sl2] = s4.z;
            else { int o = atomicAdd(ovc, 1); if (o < OVCAP) { ovf[2*o] = d4.z; ovf[2*o+1] = s4.z; } }
            if (sl3 < CAP) bucket[d4.w * CAP + sl3] = s4.w;
            else { int o = atomicAdd(ovc, 1); if (o < OVCAP) { ovf[2*o] = d4.w; ovf[2*o+1] = s4.w; } }
        }
        return;
    }
    // last block: weight folding + attention softmax
    int j = lt;
    if (j < 32) {
        float wz0 = 0.f, wz1 = 0.f, bz = 0.f, wh0 = 0.f, wh1 = 0.f, bh = 0.f;
        for (int k = 0; k < 32; ++k) {
            float lz = lzw[k * 32 + j], lh = lhw[k * 32 + j];
            wz0 = fmaf(czw[k],      lz, wz0);
            wz1 = fmaf(czw[32 + k], lz, wz1);
            bz  = fmaf(czb[k],      lz, bz);
            wh0 = fmaf(chw[k],      lh, wh0);
            wh1 = fmaf(chw[32 + k], lh, wh1);
            bh  = fmaf(chb[k],      lh, bh);
        }
        eff[j]        = -LOG2E * wz0;
        eff[32 + j]   = -LOG2E * wz1;
        eff[64 + j]   = -LOG2E * (bz + lzb[j]);
        eff[96 + j]   = 2.0f * LOG2E * wh0;
        eff[128 + j]  = 2.0f * LOG2E * wh1;
        eff[160 + j]  = 2.0f * LOG2E * (bh + lhb[j]);
    } else if (j == 32) {
        float m = -1e30f;
        for (int t = 0; t < TT; ++t) m = fmaxf(m, att[t]);
        float p[TT], s = 0.f;
        for (int t = 0; t < TT; ++t) { p[t] = __expf(att[t] - m); s += p[t]; }
        float inv = 1.0f / s;
        for (int t = 0; t < TT; ++t) eff[192 + t] = p[t] * inv;
    }
}

// ---- fused gather + gates + head: 4 nodes per wave, 2-deep pipeline -------
// Per node the serial chain bucket->cnt[src]->x-loads (~1600 cy) is issued
// 1-2 nodes ahead so it lands under the previous node's gates (~1300 cy).
// ZERO block barriers; wave-private sx/lacc; wave-redundant weight staging.
__global__ void __launch_bounds__(256)
k_fused(const float* __restrict__ x, const int* __restrict__ cnt,
        const int* __restrict__ ovc, const int* __restrict__ ovf,
        const int* __restrict__ bucket, const float* __restrict__ eff,
        const float* __restrict__ hw, const float* __restrict__ hb,
        float* __restrict__ out) {
    __shared__ __align__(16) float shwT[12 * 36]; // head_w transposed: [kk][jj], stride 36
    __shared__ float shb[12];                     // head_b
    __shared__ __align__(16) float sx[4 * NM];    // per-wave agg row, (v0,v1) paired by t
    __shared__ __align__(16) float lacc[4 * 144]; // per-wave relu'd hidden, stride 36
    const int lt = threadIdx.x, lane = lt & 63, w = lt >> 6;
    const int nbase = (blockIdx.x * 4 + w) * NPW; // 1875 blocks * 4 waves * 4 nodes

    // ---- A(0), A(1): fronts for first two nodes, issued immediately ------
    int bval[NPW + 2], cn_[NPW + 2];
    bval[0] = 0; if (lane < CAP) bval[0] = bucket[(nbase + 0) * CAP + lane];
    cn_[0] = cnt[nbase + 0];
    bval[1] = 0; if (lane < CAP) bval[1] = bucket[(nbase + 1) * CAP + lane];
    cn_[1] = cnt[nbase + 1];
    const int nov0 = *ovc;

    // ---- gate weights -> registers (fills front latency) -----------------
    const int j = lane & 31;
    const float az0 = eff[j],      az1 = eff[32 + j],  ab = eff[64 + j];
    const float ch0 = eff[96 + j], ch1 = eff[128 + j], cb = eff[160 + j];
    float pt[TT];
#pragma unroll
    for (int t = 0; t < TT; ++t) pt[t] = rfl_f(eff[192 + t]);  // force SGPR

    // ---- head weights: wave-redundant transposed LDS staging -------------
#pragma unroll
    for (int i = 0; i < 6; ++i) {
        int idx = lane + 64 * i;          // 0..383, hw[jj*12+kk]
        int jj = idx / 12, kk = idx - 12 * jj;
        shwT[kk * 36 + jj] = hw[idx];
    }
    if (lane < 12) shb[lane] = hb[lane];

    const bool act = (lane < 48);
    const int b = lane / 12, f2 = lane - 12 * b;       // valid when lane<48
    const float2* xb = (const float2*)x;
    const int lane_off = b * (NN * 12) + f2;           // float2 units
    float* const sxw = sx + w * NM + b * FT;
    const int g = (f2 < 6) ? (4 * f2) : (4 * (f2 - 6) + 1);
    const int b0_ = lane >> 5;

    int bv2[NPW + 1], cv[NPW + 1], sv[NPW + 1], mm[NPW + 1];
    float wvv[NPW + 1];
    float2 xv[12];                       // in-flight x rows (single buffer)

    // ---- B(0): clamp + speculative cnt[src] (safe: bv2 bounded, L2-hit) --
    bv2[0] = ((unsigned)bval[0] < (unsigned)NN) ? bval[0] : (nbase + 0);
    cv[0] = 0; if (lane < CAP) cv[0] = cnt[bv2[0]];
    // ---- C(0): slot map + issue node-0 x loads ---------------------------
    {
        const int deg = __builtin_amdgcn_readfirstlane(cn_[0]);
        mm[0] = (deg < CAP) ? deg : CAP;
        sv[0] = (lane < mm[0]) ? bv2[0] : (nbase + 0);
        const int cc = (lane < mm[0]) ? cv[0] : deg;
        wvv[0] = (lane <= mm[0]) ? rsqrtf((float)(cc + 1)) : 0.f;
        const float2* P[12];
#pragma unroll
        for (int q = 0; q < 12; ++q)
            P[q] = xb + (size_t)__builtin_amdgcn_readlane(sv[0], q) * 12;
        if (act) {
#pragma unroll
            for (int q = 0; q < 12; ++q) xv[q] = P[q][lane_off];
        }
    }

#pragma unroll
    for (int i = 0; i < NPW; ++i) {
        const int n = nbase + i;
        // ---- B(i+1), A(i+2): issue next fronts before consuming xv -------
        if (i + 1 < NPW) {
            bv2[i+1] = ((unsigned)bval[i+1] < (unsigned)NN) ? bval[i+1] : (n + 1);
            cv[i+1] = 0; if (lane < CAP) cv[i+1] = cnt[bv2[i+1]];
        }
        if (i + 2 < NPW) {
            bval[i+2] = 0; if (lane < CAP) bval[i+2] = bucket[(nbase + i + 2) * CAP + lane];
            cn_[i+2] = cnt[nbase + i + 2];
        }
        // ---- gather(i): consume xv (loads issued a full node ago) --------
        float2 acc = {0.f, 0.f};
        if (act) {
#pragma unroll
            for (int q = 0; q < 12; ++q) {
                float wq = readlane_f(wvv[i], q);
                acc.x = fmaf(wq, xv[q].x, acc.x);
                acc.y = fmaf(wq, xv[q].y, acc.y);
            }
        }
        // tail (deg > 11, ~11% of nodes): 4-wide groups
        const int mp1 = mm[i] + 1;
        for (int k = 12; k < mp1; k += 4) {
            int s0 = __builtin_amdgcn_readlane(sv[i], k);
            int s1 = __builtin_amdgcn_readlane(sv[i], k + 1);
            int s2 = __builtin_amdgcn_readlane(sv[i], k + 2);
            int s3 = __builtin_amdgcn_readlane(sv[i], k + 3);
            const float2* p0 = xb + (size_t)s0 * 12;
            const float2* p1 = xb + (size_t)s1 * 12;
            const float2* p2 = xb + (size_t)s2 * 12;
            const float2* p3 = xb + (size_t)s3 * 12;
            if (act) {
                float2 v0 = p0[lane_off], v1 = p1[lane_off];
                float2 v2 = p2[lane_off], v3 = p3[lane_off];
                float w0 = readlane_f(wvv[i], k),     w1 = readlane_f(wvv[i], k + 1);
                float w2 = readlane_f(wvv[i], k + 2), w3 = readlane_f(wvv[i], k + 3);
                acc.x = fmaf(w0, v0.x, acc.x); acc.y = fmaf(w0, v0.y, acc.y);
                acc.x = fmaf(w1, v1.x, acc.x); acc.y = fmaf(w1, v1.y, acc.y);
                acc.x = fmaf(w2, v2.x, acc.x); acc.y = fmaf(w2, v2.y, acc.y);
                acc.x = fmaf(w3, v3.x, acc.x); acc.y = fmaf(w3, v3.y, acc.y);
            }
        }
        // overflow edges (normally zero)
        int nov = __builtin_amdgcn_readfirstlane(nov0);
        if (nov > 0) {
            if (nov > OVCAP) nov = OVCAP;
            for (int o = 0; o < nov; ++o) {
                int d = ovf[2 * o];
                if (d == n) {
                    int s = ovf[2 * o + 1];
                    float ws_ = rsqrtf((float)(cnt[s] + 1));
                    if (act) {
                        float2 v = xb[lane_off + s * 12];
                        acc.x = fmaf(ws_, v.x, acc.x);
                        acc.y = fmaf(ws_, v.y, acc.y);
                    }
                }
            }
        }
        const float dn = readlane_f(wvv[i], mm[i]);   // rsqrt(deg_n + 1)
        if (act) {
            // paired layout: float idx 2t = v0[t], 2t+1 = v1[t]
            sxw[g]     = dn * acc.x;
            sxw[g + 2] = dn * acc.y;
        }
        // ---- C(i+1): slot map + issue next node's x loads ----------------
        // (they land under this node's gates ~1300 cy)
        if (i + 1 < NPW) {
            const int deg = __builtin_amdgcn_readfirstlane(cn_[i+1]);
            mm[i+1] = (deg < CAP) ? deg : CAP;
            sv[i+1] = (lane < mm[i+1]) ? bv2[i+1] : (n + 1);
            const int cc = (lane < mm[i+1]) ? cv[i+1] : deg;
            wvv[i+1] = (lane <= mm[i+1]) ? rsqrtf((float)(cc + 1)) : 0.f;
            const float2* P[12];
#pragma unroll
            for (int q = 0; q < 12; ++q)
                P[q] = xb + (size_t)__builtin_amdgcn_readlane(sv[i+1], q) * 12;
            if (act) {
#pragma unroll
                for (int q = 0; q < 12; ++q) xv[q] = P[q][lane_off];
            }
        }
        // within-wave LDS write->read ordering
        asm volatile("s_waitcnt lgkmcnt(0)" ::: "memory");

        // ---- gates: lane handles (b0, j) and (b0+2, j); one-sided clamp --
#pragma unroll
        for (int bi = 0; bi < 2; ++bi) {
            const int bb = b0_ + 2 * bi;
            const float4* srow4 = (const float4*)(sx + w * NM + bb * FT);
            float a0 = 0.f, a1 = 0.f;
#pragma unroll
            for (int tp = 0; tp < 6; ++tp) {
                float4 s4 = srow4[tp];   // v0[2tp], v1[2tp], v0[2tp+1], v1[2tp+1]
                float aeX = fmaf(s4.y, az1, fmaf(s4.x, az0, ab));
                float aeY = fmaf(s4.w, az1, fmaf(s4.z, az0, ab));
                float ceX = fmaf(s4.y, ch1, fmaf(s4.x, ch0, cb));
                float ceY = fmaf(s4.w, ch1, fmaf(s4.z, ch0, cb));
                // upper clamp only: exp2(-big) = 0 is the exact limit
                aeX = fminf(aeX, 24.f); aeY = fminf(aeY, 24.f);
                ceX = fminf(ceX, 24.f); ceY = fminf(ceY, 24.f);
                float uX  = __builtin_amdgcn_exp2f(aeX);
                float uY  = __builtin_amdgcn_exp2f(aeY);
                float eX  = __builtin_amdgcn_exp2f(ceX);
                float eY  = __builtin_amdgcn_exp2f(ceY);
                float t1X = 1.0f + uX,  t1Y = 1.0f + uY;
                float dX  = fmaf(eX, t1X, t1X), dY = fmaf(eY, t1Y, t1Y);
                float nX  = fmaf(uX, eX, -uX),  nY = fmaf(uY, eY, -uY);
                float rX  = __builtin_amdgcn_rcpf(dX);
                float rY  = __builtin_amdgcn_rcpf(dY);
                a0 = fmaf(pt[2 * tp] * nX, rX, a0);
                a1 = fmaf(pt[2 * tp + 1] * nY, rY, a1);
            }
            lacc[w * 144 + bb * 36 + j] = fmaxf(a0 + a1, 0.f);
        }
        asm volatile("s_waitcnt lgkmcnt(0)" ::: "memory");

        // ---- head: lanes 0..47 produce (b, k); b128 x b128 dot -----------
        if (lane < 48) {
            int bb = lane / 12, kk = lane - 12 * bb;
            float r = shb[kk];
            const float4* la4 = (const float4*)(lacc + w * 144 + bb * 36);
            const float4* wt4 = (const float4*)(shwT + kk * 36);
#pragma unroll
            for (int q = 0; q < 8; ++q) {
                float4 A = la4[q], W = wt4[q];
                r = fmaf(A.x, W.x, r); r = fmaf(A.y, W.y, r);
                r = fmaf(A.z, W.z, r); r = fmaf(A.w, W.w, r);
            }
            out[((long long)bb * NN + n) * 12 + kk] = r;
        }
    }
}

extern "C" void kernel_launch(void* const* d_in, const int* in_sizes, int n_in,
                              void* d_out, int out_size, void* d_ws, size_t ws_size,
                              hipStream_t stream) {
    const float* x   = (const float*)d_in[0];
    const int*   ei  = (const int*)d_in[1];     // (2,E): [0,E)=src, [E,2E)=dst
    const float* att = (const float*)d_in[2];
    const float* czw = (const float*)d_in[3];
    const float* czb = (const float*)d_in[4];
    const float* lzw = (const float*)d_in[5];
    const float* lzb = (const float*)d_in[6];
    // d_in[7..10] (conv_r / lin_r) dead: H0 == 0 so H0*R == 0
    const float* chw = (const float*)d_in[11];
    const float* chb = (const float*)d_in[12];
    const float* lhw = (const float*)d_in[13];
    const float* lhb = (const float*)d_in[14];
    const float* hw  = (const float*)d_in[15];
    const float* hb  = (const float*)d_in[16];
    float* out = (float*)d_out;

    float* ws = (float*)d_ws;
    int*   cnt = (int*)(ws + WS_CNT);
    int*   ovc = (int*)(ws + WS_OVC);
    float* eff = ws + WS_EFF;
    int*   ovf = (int*)(ws + WS_OVF);
    int*   bkt = (int*)(ws + WS_BKT);

    const int* src = ei;
    const int* dst = ei + EE;

    hipMemsetAsync(cnt, 0, WS_EFF * 4, stream);   // zero cnt + ovf_cnt
    k_pre<<<FB + 1, 256, 0, stream>>>(src, dst, czw, czb, lzw, lzb,
                                      chw, chb, lhw, lhb, att,
                                      cnt, ovc, ovf, bkt, eff);
    k_fused<<<NN / (4 * NPW), 256, 0, stream>>>(x, cnt, ovc, ovf, bkt, eff, hw, hb, out);
}

// Round 6
// 135.624 us; speedup vs baseline: 1.0292x; 1.0292x over previous
//
#include <hip/hip_runtime.h>

// Problem constants
#define BB   4
#define NN   30000
#define TT   12
#define EE   240000
#define FT   24        // F_IN * T floats per (b, node)
#define NM   96        // BB * FT
#define CAP  32        // bucket capacity per node (deg ~ Poisson(8); max ~22)
#define OVCAP 2048     // overflow capacity (normally 0 used)
#define FB   ((EE + 1023) / 1024)    // 235 fill blocks (4 edges/thread)
#define LOG2E 1.44269504088896340736f

// Workspace layout (4-byte elements), total ~4 MB:
//   cnt[NN]          @ 0            (zeroed by memset)
//   ovf_cnt[16]      @ 30000        (zeroed by memset; [0] used)
//   eff[256]  float  @ 30016
//   ovf[2*OVCAP] int @ 30272        ((dst,src) pairs)
//   bucket[NN*CAP]   @ 34368
#define WS_CNT 0
#define WS_OVC 30000
#define WS_EFF 30016
#define WS_OVF 30272
#define WS_BKT 34368

__device__ __forceinline__ float readlane_f(float v, int l) {
    return __int_as_float(__builtin_amdgcn_readlane(__float_as_int(v), l));
}
__device__ __forceinline__ float rfl_f(float v) {
    return __int_as_float(__builtin_amdgcn_readfirstlane(__float_as_int(v)));
}

// ---- one launch: bucket-fill (4 edges/thread) | weight fold ---------------
// eff layout: Az0[32] Az1[32] ab[32] Ch0[32] Ch1[32] cb[32] probs[12]
// where A* = -log2e * (Wz folded), C* = 2*log2e * (Wh folded):
//   a = Az0*v0 + Az1*v1 + ab  -> u  = exp2(a) = exp(-zp)
//   c = Ch0*v0 + Ch1*v1 + cb  -> e2 = exp2(c) = exp(2*hp)
__global__ void __launch_bounds__(256)
k_pre(const int* __restrict__ src, const int* __restrict__ dst,
      const float* __restrict__ czw, const float* __restrict__ czb,
      const float* __restrict__ lzw, const float* __restrict__ lzb,
      const float* __restrict__ chw, const float* __restrict__ chb,
      const float* __restrict__ lhw, const float* __restrict__ lhb,
      const float* __restrict__ att,
      int* __restrict__ cnt, int* __restrict__ ovc,
      int* __restrict__ ovf, int* __restrict__ bucket, float* __restrict__ eff) {
    int bid = blockIdx.x, lt = threadIdx.x;
    if (bid < FB) {
        int e = bid * 1024 + lt * 4;           // EE % 4 == 0 -> all-or-nothing
        if (e < EE) {
            int4 s4 = *(const int4*)(src + e);
            int4 d4 = *(const int4*)(dst + e);
            // 4 independent atomic chains in flight
            int sl0 = atomicAdd(&cnt[d4.x], 1);
            int sl1 = atomicAdd(&cnt[d4.y], 1);
            int sl2 = atomicAdd(&cnt[d4.z], 1);
            int sl3 = atomicAdd(&cnt[d4.w], 1);
            if (sl0 < CAP) bucket[d4.x * CAP + sl0] = s4.x;
            else { int o = atomicAdd(ovc, 1); if (o < OVCAP) { ovf[2*o] = d4.x; ovf[2*o+1] = s4.x; } }
            if (sl1 < CAP) bucket[d4.y * CAP + sl1] = s4.y;
            else { int o = atomicAdd(ovc, 1); if (o < OVCAP) { ovf[2*o] = d4.y; ovf[2*o+1] = s4.y; } }
            if (sl2 < CAP) bucket[d4.z * CAP + sl2] = s4.z;
            else { int o = atomicAdd(ovc, 1); if (o < OVCAP) { ovf[2*o] = d4.z; ovf[2*o+1] = s4.z; } }
            if (sl3 < CAP) bucket[d4.w * CAP + sl3] = s4.w;
            else { int o = atomicAdd(ovc, 1); if (o < OVCAP) { ovf[2*o] = d4.w; ovf[2*o+1] = s4.w; } }
        }
        return;
    }
    // last block: weight folding + attention softmax
    int j = lt;
    if (j < 32) {
        float wz0 = 0.f, wz1 = 0.f, bz = 0.f, wh0 = 0.f, wh1 = 0.f, bh = 0.f;
        for (int k = 0; k < 32; ++k) {
            float lz = lzw[k * 32 + j], lh = lhw[k * 32 + j];
            wz0 = fmaf(czw[k],      lz, wz0);
            wz1 = fmaf(czw[32 + k], lz, wz1);
            bz  = fmaf(czb[k],      lz, bz);
            wh0 = fmaf(chw[k],      lh, wh0);
            wh1 = fmaf(chw[32 + k], lh, wh1);
            bh  = fmaf(chb[k],      lh, bh);
        }
        eff[j]        = -LOG2E * wz0;
        eff[32 + j]   = -LOG2E * wz1;
        eff[64 + j]   = -LOG2E * (bz + lzb[j]);
        eff[96 + j]   = 2.0f * LOG2E * wh0;
        eff[128 + j]  = 2.0f * LOG2E * wh1;
        eff[160 + j]  = 2.0f * LOG2E * (bh + lhb[j]);
    } else if (j == 32) {
        float m = -1e30f;
        for (int t = 0; t < TT; ++t) m = fmaxf(m, att[t]);
        float p[TT], s = 0.f;
        for (int t = 0; t < TT; ++t) { p[t] = __expf(att[t] - m); s += p[t]; }
        float inv = 1.0f / s;
        for (int t = 0; t < TT; ++t) eff[192 + t] = p[t] * inv;
    }
}

// ---- fused gather + gates + head: one wave per node -----------------------
// Latency is hidden by TLP (7500 blocks, ~8 blocks/CU resident) — round 5
// proved that trading wave count for in-wave pipelining regresses.
// Flat 12-slot gather issue (one HBM round-trip covers deg<=11, ~89% of
// nodes; padded slots clamp to row n -> L1 hits, weight 0).
// ZERO block barriers; wave-private sx/lacc; wave-redundant weight staging.
__global__ void __launch_bounds__(256)
k_fused(const float* __restrict__ x, const int* __restrict__ cnt,
        const int* __restrict__ ovc, const int* __restrict__ ovf,
        const int* __restrict__ bucket, const float* __restrict__ eff,
        const float* __restrict__ hw, const float* __restrict__ hb,
        float* __restrict__ out) {
    __shared__ __align__(16) float shwT[12 * 36]; // head_w transposed: [kk][jj], stride 36
    __shared__ float shb[12];                     // head_b
    __shared__ __align__(16) float sx[4 * NM];    // per-wave agg row, (v0,v1) paired by t
    __shared__ __align__(16) float lacc[4 * 144]; // per-wave relu'd hidden, stride 36
    const int lt = threadIdx.x, lane = lt & 63, w = lt >> 6;
    const int n = blockIdx.x * 4 + w;  // 7500 blocks * 4 waves = 30000 nodes

    // ---- front-end loads first: addresses depend only on blockIdx --------
    int bval = 0;
    if (lane < CAP) bval = bucket[n * CAP + lane];
    const int cn  = cnt[n];
    const int nov0 = *ovc;

    // ---- gate weights straight to registers (coalesced: j = lane&31) -----
    const int j = lane & 31;
    const float az0 = eff[j],      az1 = eff[32 + j],  ab = eff[64 + j];
    const float ch0 = eff[96 + j], ch1 = eff[128 + j], cb = eff[160 + j];
    float pt[TT];
#pragma unroll
    for (int t = 0; t < TT; ++t) pt[t] = rfl_f(eff[192 + t]);  // force SGPR

    // ---- head weights: wave-redundant transposed LDS staging -------------
#pragma unroll
    for (int i = 0; i < 6; ++i) {
        int idx = lane + 64 * i;          // 0..383, hw[jj*12+kk]
        int jj = idx / 12, kk = idx - 12 * jj;
        shwT[kk * 36 + jj] = hw[idx];
    }
    if (lane < 12) shb[lane] = hb[lane];

    const bool act = (lane < 48);
    const int b = lane / 12, f2 = lane - 12 * b;       // valid when lane<48
    const float2* xb = (const float2*)x;
    const int lane_off = b * (NN * 12) + f2;           // float2 units

    // Speculative: cnt[spec-src] issued as soon as the bucket row lands
    // (clamped -> safe on stale/poison slots; cnt is L2-resident).
    const int bv2 = ((unsigned)bval < (unsigned)NN) ? bval : n;
    int cv = 0;
    if (lane < CAP) cv = cnt[bv2];

    const int deg = __builtin_amdgcn_readfirstlane(cn);
    const int m = (deg < CAP) ? deg : CAP;
    const int mp1 = m + 1;                              // used slots incl self
    // lane m = self loop (sv=n, wv=dn); lanes > m: sv=n, wv=0.
    const int sv = (lane < m) ? bv2 : n;
    const int cc = (lane < m) ? cv : deg;               // lanes >= m see deg -> dn
    const float wv = (lane <= m) ? rsqrtf((float)(cc + 1)) : 0.f;

    float2 acc = {0.f, 0.f};
    // ---- flat 12-slot issue: all loads in flight before any FMA -----------
    {
        const float2* P[12];
#pragma unroll
        for (int i = 0; i < 12; ++i) {
            int si = __builtin_amdgcn_readlane(sv, i);   // uniform -> SGPR
            P[i] = xb + (size_t)si * 12;
        }
        if (act) {
            float2 v0  = P[0][lane_off],  v1  = P[1][lane_off];
            float2 v2  = P[2][lane_off],  v3  = P[3][lane_off];
            float2 v4  = P[4][lane_off],  v5  = P[5][lane_off];
            float2 v6  = P[6][lane_off],  v7  = P[7][lane_off];
            float2 v8  = P[8][lane_off],  v9  = P[9][lane_off];
            float2 v10 = P[10][lane_off], v11 = P[11][lane_off];
            float w0 = readlane_f(wv, 0),  w1 = readlane_f(wv, 1);
            float w2 = readlane_f(wv, 2),  w3 = readlane_f(wv, 3);
            float w4 = readlane_f(wv, 4),  w5 = readlane_f(wv, 5);
            float w6 = readlane_f(wv, 6),  w7 = readlane_f(wv, 7);
            float w8 = readlane_f(wv, 8),  w9 = readlane_f(wv, 9);
            float w10 = readlane_f(wv, 10), w11 = readlane_f(wv, 11);
            acc.x = fmaf(w0, v0.x, acc.x);   acc.y = fmaf(w0, v0.y, acc.y);
            acc.x = fmaf(w1, v1.x, acc.x);   acc.y = fmaf(w1, v1.y, acc.y);
            acc.x = fmaf(w2, v2.x, acc.x);   acc.y = fmaf(w2, v2.y, acc.y);
            acc.x = fmaf(w3, v3.x, acc.x);   acc.y = fmaf(w3, v3.y, acc.y);
            acc.x = fmaf(w4, v4.x, acc.x);   acc.y = fmaf(w4, v4.y, acc.y);
            acc.x = fmaf(w5, v5.x, acc.x);   acc.y = fmaf(w5, v5.y, acc.y);
            acc.x = fmaf(w6, v6.x, acc.x);   acc.y = fmaf(w6, v6.y, acc.y);
            acc.x = fmaf(w7, v7.x, acc.x);   acc.y = fmaf(w7, v7.y, acc.y);
            acc.x = fmaf(w8, v8.x, acc.x);   acc.y = fmaf(w8, v8.y, acc.y);
            acc.x = fmaf(w9, v9.x, acc.x);   acc.y = fmaf(w9, v9.y, acc.y);
            acc.x = fmaf(w10, v10.x, acc.x); acc.y = fmaf(w10, v10.y, acc.y);
            acc.x = fmaf(w11, v11.x, acc.x); acc.y = fmaf(w11, v11.y, acc.y);
        }
    }
    // ---- tail (deg > 11, ~11% of nodes): 4-wide groups --------------------
    for (int k = 12; k < mp1; k += 4) {
        int s0 = __builtin_amdgcn_readlane(sv, k);
        int s1 = __builtin_amdgcn_readlane(sv, k + 1);
        int s2 = __builtin_amdgcn_readlane(sv, k + 2);
        int s3 = __builtin_amdgcn_readlane(sv, k + 3);
        const float2* p0 = xb + (size_t)s0 * 12;
        const float2* p1 = xb + (size_t)s1 * 12;
        const float2* p2 = xb + (size_t)s2 * 12;
        const float2* p3 = xb + (size_t)s3 * 12;
        if (act) {
            float2 v0 = p0[lane_off], v1 = p1[lane_off];
            float2 v2 = p2[lane_off], v3 = p3[lane_off];
            float w0 = readlane_f(wv, k),     w1 = readlane_f(wv, k + 1);
            float w2 = readlane_f(wv, k + 2), w3 = readlane_f(wv, k + 3);
            acc.x = fmaf(w0, v0.x, acc.x); acc.y = fmaf(w0, v0.y, acc.y);
            acc.x = fmaf(w1, v1.x, acc.x); acc.y = fmaf(w1, v1.y, acc.y);
            acc.x = fmaf(w2, v2.x, acc.x); acc.y = fmaf(w2, v2.y, acc.y);
            acc.x = fmaf(w3, v3.x, acc.x); acc.y = fmaf(w3, v3.y, acc.y);
        }
    }

    // overflow edges (normally zero)
    int nov = __builtin_amdgcn_readfirstlane(nov0);
    if (nov > 0) {
        if (nov > OVCAP) nov = OVCAP;
        for (int i = 0; i < nov; ++i) {
            int d = ovf[2 * i];
            if (d == n) {
                int s = ovf[2 * i + 1];
                float ws_ = rsqrtf((float)(cnt[s] + 1));
                if (act) {
                    float2 v = xb[lane_off + s * 12];
                    acc.x = fmaf(ws_, v.x, acc.x);
                    acc.y = fmaf(ws_, v.y, acc.y);
                }
            }
        }
    }

    const float dn = readlane_f(wv, m);   // rsqrt(deg_n + 1)
    if (act) {
        // paired layout: float idx 2t = v0[t], 2t+1 = v1[t]
        // lane f2<6 holds (f=0, t=2f2, 2f2+1) -> idx 4f2, 4f2+2
        // lane f2>=6 holds (f=1, t=2(f2-6), ..) -> idx 4(f2-6)+1, +3
        float* sxw = sx + w * NM + b * FT;
        const int g = (f2 < 6) ? (4 * f2) : (4 * (f2 - 6) + 1);
        sxw[g]     = dn * acc.x;
        sxw[g + 2] = dn * acc.y;
    }

    // within-wave LDS write->read ordering (replaces __syncthreads)
    asm volatile("s_waitcnt lgkmcnt(0)" ::: "memory");

    // ---- gates: lane handles (b0, j) and (b0+2, j); paired t, merged rcp --
    const int b0_ = lane >> 5;
#pragma unroll
    for (int bi = 0; bi < 2; ++bi) {
        const int bb = b0_ + 2 * bi;
        const float4* srow4 = (const float4*)(sx + w * NM + bb * FT);
        float a0 = 0.f, a1 = 0.f;
#pragma unroll
        for (int tp = 0; tp < 6; ++tp) {
            float4 s4 = srow4[tp];   // v0[2tp], v1[2tp], v0[2tp+1], v1[2tp+1]
            float aeX = fmaf(s4.y, az1, fmaf(s4.x, az0, ab));
            float aeY = fmaf(s4.w, az1, fmaf(s4.z, az0, ab));
            float ceX = fmaf(s4.y, ch1, fmaf(s4.x, ch0, cb));
            float ceY = fmaf(s4.w, ch1, fmaf(s4.z, ch0, cb));
            // upper clamp only: exp2(-big) = 0 is the exact limit
            aeX = fminf(aeX, 24.f); aeY = fminf(aeY, 24.f);
            ceX = fminf(ceX, 24.f); ceY = fminf(ceY, 24.f);
            float uX  = __builtin_amdgcn_exp2f(aeX);
            float uY  = __builtin_amdgcn_exp2f(aeY);
            float eX  = __builtin_amdgcn_exp2f(ceX);
            float eY  = __builtin_amdgcn_exp2f(ceY);
            float t1X = 1.0f + uX,  t1Y = 1.0f + uY;
            float dX  = fmaf(eX, t1X, t1X), dY = fmaf(eY, t1Y, t1Y);
            float nX  = fmaf(uX, eX, -uX),  nY = fmaf(uY, eY, -uY);
            float rX  = __builtin_amdgcn_rcpf(dX);
            float rY  = __builtin_amdgcn_rcpf(dY);
            a0 = fmaf(pt[2 * tp] * nX, rX, a0);
            a1 = fmaf(pt[2 * tp + 1] * nY, rY, a1);
        }
        lacc[w * 144 + bb * 36 + j] = fmaxf(a0 + a1, 0.f);
    }
    asm volatile("s_waitcnt lgkmcnt(0)" ::: "memory");

    // ---- head: lanes 0..47 produce (b, k); b128 x b128 dot ---------------
    if (lane < 48) {
        int bb = lane / 12, kk = lane - 12 * bb;
        float r = shb[kk];
        const float4* la4 = (const float4*)(lacc + w * 144 + bb * 36);
        const float4* wt4 = (const float4*)(shwT + kk * 36);
#pragma unroll
        for (int q = 0; q < 8; ++q) {
            float4 A = la4[q], W = wt4[q];
            r = fmaf(A.x, W.x, r); r = fmaf(A.y, W.y, r);
            r = fmaf(A.z, W.z, r); r = fmaf(A.w, W.w, r);
        }
        out[((long long)bb * NN + n) * 12 + kk] = r;
    }
}

extern "C" void kernel_launch(void* const* d_in, const int* in_sizes, int n_in,
                              void* d_out, int out_size, void* d_ws, size_t ws_size,
                              hipStream_t stream) {
    const float* x   = (const float*)d_in[0];
    const int*   ei  = (const int*)d_in[1];     // (2,E): [0,E)=src, [E,2E)=dst
    const float* att = (const float*)d_in[2];
    const float* czw = (const float*)d_in[3];
    const float* czb = (const float*)d_in[4];
    const float* lzw = (const float*)d_in[5];
    const float* lzb = (const float*)d_in[6];
    // d_in[7..10] (conv_r / lin_r) dead: H0 == 0 so H0*R == 0
    const float* chw = (const float*)d_in[11];
    const float* chb = (const float*)d_in[12];
    const float* lhw = (const float*)d_in[13];
    const float* lhb = (const float*)d_in[14];
    const float* hw  = (const float*)d_in[15];
    const float* hb  = (const float*)d_in[16];
    float* out = (float*)d_out;

    float* ws = (float*)d_ws;
    int*   cnt = (int*)(ws + WS_CNT);
    int*   ovc = (int*)(ws + WS_OVC);
    float* eff = ws + WS_EFF;
    int*   ovf = (int*)(ws + WS_OVF);
    int*   bkt = (int*)(ws + WS_BKT);

    const int* src = ei;
    const int* dst = ei + EE;

    hipMemsetAsync(cnt, 0, WS_EFF * 4, stream);   // zero cnt + ovf_cnt
    k_pre<<<FB + 1, 256, 0, stream>>>(src, dst, czw, czb, lzw, lzb,
                                      chw, chb, lhw, lhb, att,
                                      cnt, ovc, ovf, bkt, eff);
    k_fused<<<NN / 4, 256, 0, stream>>>(x, cnt, ovc, ovf, bkt, eff, hw, hb, out);
}